// Round 7
// baseline (216.586 us; speedup 1.0000x reference)
//
#include <hip/hip_runtime.h>
#include <hip/hip_bf16.h>

// Conv2d 3x3 s1p1: x(32,128,56,56) f32, w(256,128,3,3) f32, bias(256) -> (32,256,56,56) f32.
// R6: conv_main = 256x128 tile (BM=256=all COUT, BN=128), 512 thr = 8 waves (4M x 2N,
// 64x64/wave), BK=32, THREE LDS buffers (72 KB -> 2 blocks/CU = 16 waves/CU),
// distance-2 prefetch: iter t waits vmcnt(3) (tile t landed, t+1 in flight - never 0),
// ONE barrier/iter, stages tile t+2, 8 ds_read_b128 + 16 MFMA (setprio).
// Staging bytes/FLOP -25% vs R5; R4's validated 64B-row/4-seg LDS swizzle reused verbatim.
// prep_x / prep_w unchanged.

#define CIN   128
#define HH    56
#define WW    56
#define COUT  256
#define HW    3136
#define NIMG  32
#define NP    (NIMG * HW)            // 100352 = 784 * 128
#define XPW   58
#define XPIX  (XPW * XPW)            // 3364
#define XPAD_BYTES (NIMG * XPIX * CIN * 2)   // 27,566,080
#define WT_OFF     XPAD_BYTES

typedef __bf16 bf16x8 __attribute__((ext_vector_type(8)));
typedef float  f32x4  __attribute__((ext_vector_type(4)));

#define GLD16(g, l) __builtin_amdgcn_global_load_lds( \
    (const __attribute__((address_space(1))) void*)(g), \
    (__attribute__((address_space(3))) void*)(l), 16, 0, 0)

// ---- pre-pass 1: x NCHW f32 -> xpad NHWC bf16 with 1-px halo; writes own halo zeros.
__global__ __launch_bounds__(128) void prep_x(const float* __restrict__ x,
                                              __hip_bfloat16* __restrict__ xp) {
    __shared__ unsigned short t[HH * CIN];   // [x][ci], 14336 B
    const int b  = blockIdx.x;               // 32*56
    const int n  = b / HH;
    const int y  = b - n * HH;
    const int ci = threadIdx.x;              // 0..127

    const float* src = x + ((size_t)(n * CIN + ci) * HW) + y * WW;
    #pragma unroll
    for (int j = 0; j < 14; ++j) {           // 56 floats, per-lane contiguous stream
        const float4 v = ((const float4*)src)[j];
        t[(4 * j + 0) * CIN + ci] = (unsigned short)(__float_as_uint(v.x) >> 16);
        t[(4 * j + 1) * CIN + ci] = (unsigned short)(__float_as_uint(v.y) >> 16);
        t[(4 * j + 2) * CIN + ci] = (unsigned short)(__float_as_uint(v.z) >> 16);
        t[(4 * j + 3) * CIN + ci] = (unsigned short)(__float_as_uint(v.w) >> 16);
    }

    const uint4 z = make_uint4(0, 0, 0, 0);
    if (ci < 32) {
        const int side = ci >> 4;            // 0 = x'=0, 1 = x'=57
        const int j    = ci & 15;
        ((uint4*)(xp + ((size_t)n * XPIX + (y + 1) * XPW + side * 57) * CIN))[j] = z;
    }
    if (y == 0)
        for (int j = ci; j < 928; j += 128)  // row 0: 58*128 bf16 = 928 uint4
            ((uint4*)(xp + (size_t)n * XPIX * CIN))[j] = z;
    if (y == HH - 1)
        for (int j = ci; j < 928; j += 128)  // row 57
            ((uint4*)(xp + ((size_t)n * XPIX + 57 * XPW) * CIN))[j] = z;

    __syncthreads();

    uint4* dst = (uint4*)(xp + ((size_t)n * XPIX + (y + 1) * XPW + 1) * CIN);
    const uint4* lsrc = (const uint4*)t;
    #pragma unroll
    for (int j = 0; j < 7; ++j)
        dst[j * 128 + ci] = lsrc[j * 128 + ci];
}

// ---- pre-pass 2: w (co,ci,3,3) f32 -> Wt[tap][co][ci] bf16
__global__ __launch_bounds__(256) void prep_w(const float* __restrict__ w,
                                              __hip_bfloat16* __restrict__ wt) {
    const int co = blockIdx.x * 2 + (threadIdx.x >> 7);
    const int ci = threadIdx.x & 127;
    const float* src = w + (size_t)(co * CIN + ci) * 9;
    #pragma unroll
    for (int tp = 0; tp < 9; ++tp)
        wt[(size_t)tp * (COUT * CIN) + co * CIN + ci] = __float2bfloat16(src[tp]);
}

// ---- main: implicit GEMM over taps; K = 9 taps * 128 ci = 1152 = 36 K-tiles of 32.
// LDS rows are 64 B (4 segs of 16 B). Swizzle (validated in R4, conflicts=0):
//   LDS seg s of row R holds global seg s ^ ((R>>1)&3)
//   store side (lane-only): gseg = (l&3) ^ ((l>>3)&3)
//   read  side (lane-only): segoff = (quad ^ ((l15>>1)&3)) << 4
// 3 buffers x (A 16KB + B 8KB) = 72 KB -> 2 blocks/CU.
__global__ __launch_bounds__(512, 4) void conv_main(
    const char* __restrict__ xpb,
    const char* __restrict__ wtb,
    const float* __restrict__ bias,
    float* __restrict__ out)
{
    __shared__ __align__(16) char L[73728];  // buf b at b*24576: A [0,16384), B [16384,24576)

    const int tid  = threadIdx.x;
    const int l    = tid & 63;
    const int wv   = tid >> 6;               // 0..7
    const int wm   = wv >> 1;                // 0..3  (M: 64 rows each)
    const int wn   = wv & 1;                 // 0..1  (N: 64 rows each)
    const int l15  = l & 15;
    const int quad = l >> 4;

    // XCD swizzle: 784 = 8*98, bijective chunked map.
    const int idx = blockIdx.x;
    const int bn  = (idx & 7) * 98 + (idx >> 3);
    const int pbase = bn * 128;

    // staging: A chunks c = wv*2+j (16 chunks x 16 rows); B chunk c = wv (8 x 16 rows).
    // lane -> row c*16 + (l>>2), LDS seg l&3, global seg gseg (lane-only).
    const int gseg = (l & 3) ^ ((l >> 3) & 3);
    unsigned aoff[2];
    #pragma unroll
    for (int j = 0; j < 2; ++j) {
        const int rA = (wv * 2 + j) * 16 + (l >> 2);     // 0..255 = co
        aoff[j] = (unsigned)(rA * 256 + gseg * 16);      // co-row pitch 256 B in Wt
    }
    unsigned boff;
    {
        const int rB  = wv * 16 + (l >> 2);              // 0..127
        const int p   = pbase + rB;
        const int n   = p / HW;
        const int rem = p - n * HW;
        const int y   = rem / WW;
        const int x   = rem - y * WW;
        boff = (unsigned)((n * XPIX + y * XPW + x) * 256 + gseg * 16);
    }
    const int segoff = (quad ^ ((l15 >> 1) & 3)) << 4;   // lane-only read swizzle

    f32x4 acc[4][4];
    #pragma unroll
    for (int i = 0; i < 4; ++i)
        #pragma unroll
        for (int j = 0; j < 4; ++j)
            acc[i][j] = (f32x4){0.f, 0.f, 0.f, 0.f};

    // K-tile s: tap tp = s>>2, ci-quarter kq = s&3 (bytes kq*64 within 256 B ci-row)
    auto STAGE = [&](int s, int bufw) {
        const int tp = s >> 2;
        const int kq = s & 3;
        const int r  = tp / 3;
        const int sx = tp - 3 * r;
        const unsigned wo = (unsigned)(tp * (COUT * CIN * 2) + kq * 64);
        const unsigned bo = (unsigned)((r * XPW + sx) * 256 + kq * 64);
        char* Ab = L + bufw * 24576;
        char* Bb = Ab + 16384;
        #pragma unroll
        for (int j = 0; j < 2; ++j)
            GLD16(wtb + wo + aoff[j], Ab + (wv * 2 + j) * 1024);
        GLD16(xpb + bo + boff, Bb + wv * 1024);
    };

    // prologue: tiles 0,1 in flight (6 loads/thread)
    STAGE(0, 0);
    STAGE(1, 1);

    #pragma unroll
    for (int t = 0; t < 36; ++t) {
        // wait tile t's 3 loads (tile t+1's 3 stay in flight; never 0 in loop)
        asm volatile("s_waitcnt vmcnt(3)" ::: "memory");
        __builtin_amdgcn_s_barrier();
        asm volatile("" ::: "memory");       // no LDS-read hoisting above barrier

        // stage tile t+2 into buf[(t+2)%3] (its last read was iter t-1, pre-barrier).
        // tail: dummy re-stage of 35 into dead buffers keeps vmcnt arithmetic uniform.
        STAGE((t + 2 < 36) ? t + 2 : 35, (t + 2) % 3);

        const char* Ab = L + (t % 3) * 24576;
        const char* Bb = Ab + 16384;
        bf16x8 af[4], bf[4];
        #pragma unroll
        for (int mt = 0; mt < 4; ++mt)
            af[mt] = *(const bf16x8*)(Ab + (wm * 64 + mt * 16 + l15) * 64 + segoff);
        #pragma unroll
        for (int nt = 0; nt < 4; ++nt)
            bf[nt] = *(const bf16x8*)(Bb + (wn * 64 + nt * 16 + l15) * 64 + segoff);

        __builtin_amdgcn_s_setprio(1);
        #pragma unroll
        for (int mt = 0; mt < 4; ++mt)
            #pragma unroll
            for (int nt = 0; nt < 4; ++nt)
                acc[mt][nt] = __builtin_amdgcn_mfma_f32_16x16x32_bf16(
                    af[mt], bf[nt], acc[mt][nt], 0, 0, 0);
        __builtin_amdgcn_s_setprio(0);
    }

    // drain trailing dummy loads before LDS goes out of scope
    asm volatile("s_waitcnt vmcnt(0)" ::: "memory");

    // epilogue: D[m = quad*4+reg][n = l15]; out (N, C_out, H, W)
    #pragma unroll
    for (int nt = 0; nt < 4; ++nt) {
        const int pp = pbase + wn * 64 + nt * 16 + l15;
        const int n2 = pp / HW;
        const int r2 = pp - n2 * HW;
        float* ob = out + (size_t)n2 * (COUT * HW) + r2;
        #pragma unroll
        for (int mt = 0; mt < 4; ++mt) {
            const int co = wm * 64 + mt * 16 + quad * 4;
            const float4 bv = *(const float4*)(bias + co);
            f32x4 a = acc[mt][nt];
            ob[(size_t)(co + 0) * HW] = a[0] + bv.x;
            ob[(size_t)(co + 1) * HW] = a[1] + bv.y;
            ob[(size_t)(co + 2) * HW] = a[2] + bv.z;
            ob[(size_t)(co + 3) * HW] = a[3] + bv.w;
        }
    }
}

extern "C" void kernel_launch(void* const* d_in, const int* in_sizes, int n_in,
                              void* d_out, int out_size, void* d_ws, size_t ws_size,
                              hipStream_t stream) {
    const float* x = (const float*)d_in[0];
    const float* w = (const float*)d_in[1];
    const float* b = (const float*)d_in[2];
    char* ws = (char*)d_ws;                      // needs >= 28.2 MB
    __hip_bfloat16* xp = (__hip_bfloat16*)ws;
    __hip_bfloat16* wt = (__hip_bfloat16*)(ws + WT_OFF);

    prep_x<<<dim3(NIMG * HH), dim3(128), 0, stream>>>(x, xp);
    prep_w<<<dim3(128), dim3(256), 0, stream>>>(w, wt);
    conv_main<<<dim3(NP / 128), dim3(512), 0, stream>>>(
        (const char*)xp, (const char*)wt, b, (float*)d_out);
}